// Round 1
// baseline (7074.301 us; speedup 1.0000x reference)
//
#include <hip/hip_runtime.h>
#include <math.h>

#define N_NODES  200000
#define N_EDGES  6400000
#define N_GRAPHS 64

// ---------------------------------------------------------------------------
// Pass 1: per edge, scatter concat(edge_feat[e], node_feat[src[e]]) into
// agg1[dst] (11 floats) and count in-degree.
// ---------------------------------------------------------------------------
__global__ __launch_bounds__(256) void edge_pass1(
    const float* __restrict__ edge_feat,
    const float* __restrict__ node_feat,
    const int* __restrict__ src,
    const int* __restrict__ dst,
    float* __restrict__ agg1,
    float* __restrict__ deg) {
  int e = blockIdx.x * blockDim.x + threadIdx.x;
  if (e >= N_EDGES) return;
  int s = src[e];
  int d = dst[e];
  const float4 ef = *reinterpret_cast<const float4*>(edge_feat + (size_t)e * 4);
  float* a = agg1 + (size_t)d * 11;
  atomicAdd(a + 0, ef.x);
  atomicAdd(a + 1, ef.y);
  atomicAdd(a + 2, ef.z);
  atomicAdd(a + 3, ef.w);
  const float* nf = node_feat + (size_t)s * 7;
#pragma unroll
  for (int k = 0; k < 7; ++k) atomicAdd(a + 4 + k, nf[k]);
  atomicAdd(deg + d, 1.0f);
}

// ---------------------------------------------------------------------------
// MLP 1: h1 = relu(relu(mean1 @ W1a + b1a) @ W1b + b1b), one thread per node.
// ---------------------------------------------------------------------------
__global__ __launch_bounds__(256) void mlp1(
    const float* __restrict__ agg1,
    const float* __restrict__ deg,
    const float* __restrict__ W1a, const float* __restrict__ b1a,
    const float* __restrict__ W1b, const float* __restrict__ b1b,
    float* __restrict__ h1) {
  __shared__ float sW1a[11 * 32];
  __shared__ float sW1b[32 * 32];
  __shared__ float sb1a[32];
  __shared__ float sb1b[32];
  for (int i = threadIdx.x; i < 11 * 32; i += blockDim.x) sW1a[i] = W1a[i];
  for (int i = threadIdx.x; i < 32 * 32; i += blockDim.x) sW1b[i] = W1b[i];
  if (threadIdx.x < 32) {
    sb1a[threadIdx.x] = b1a[threadIdx.x];
    sb1b[threadIdx.x] = b1b[threadIdx.x];
  }
  __syncthreads();
  int n = blockIdx.x * blockDim.x + threadIdx.x;
  if (n >= N_NODES) return;
  float inv = 1.0f / fmaxf(deg[n], 1.0f);
  float m[11];
  const float* a = agg1 + (size_t)n * 11;
#pragma unroll
  for (int i = 0; i < 11; ++i) m[i] = a[i] * inv;
  float t[32];
#pragma unroll
  for (int j = 0; j < 32; ++j) {
    float acc = sb1a[j];
#pragma unroll
    for (int i = 0; i < 11; ++i) acc += m[i] * sW1a[i * 32 + j];
    t[j] = fmaxf(acc, 0.0f);
  }
  float* out = h1 + (size_t)n * 32;
#pragma unroll
  for (int j = 0; j < 32; ++j) {
    float acc = sb1b[j];
#pragma unroll
    for (int i = 0; i < 32; ++i) acc += t[i] * sW1b[i * 32 + j];
    out[j] = fmaxf(acc, 0.0f);
  }
}

// ---------------------------------------------------------------------------
// Pass 2: 32 lanes per edge. lane k: agg2[dst*32+k] += h1[src*32+k].
// Coalesced 128B gather per edge; consecutive-address atomics.
// ---------------------------------------------------------------------------
__global__ __launch_bounds__(256) void edge_pass2(
    const float* __restrict__ h1,
    const int* __restrict__ src,
    const int* __restrict__ dst,
    float* __restrict__ agg2) {
  const long long total = (long long)N_EDGES * 32;
  long long idx = (long long)blockIdx.x * blockDim.x + threadIdx.x;
  const long long stride = (long long)gridDim.x * blockDim.x;
  const int lane = threadIdx.x & 31;
  for (; idx < total; idx += stride) {
    int e = (int)(idx >> 5);
    int s = src[e];
    int d = dst[e];
    float v = h1[(size_t)s * 32 + lane];
    atomicAdd(agg2 + (size_t)d * 32 + lane, v);
  }
}

// ---------------------------------------------------------------------------
// MLP 2 fused with per-graph max pooling (h2 never materialized).
// pooled is uint-reinterpreted f32 (all values >= 0 post-ReLU, init 0).
// ---------------------------------------------------------------------------
__global__ __launch_bounds__(256) void mlp2_pool(
    const float* __restrict__ agg2,
    const float* __restrict__ deg,
    const int* __restrict__ graph_ids,
    const float* __restrict__ W2a, const float* __restrict__ b2a,
    const float* __restrict__ W2b, const float* __restrict__ b2b,
    unsigned int* __restrict__ pooled_u) {
  __shared__ float sW2a[32 * 32];
  __shared__ float sW2b[32 * 32];
  __shared__ float sb2a[32];
  __shared__ float sb2b[32];
  for (int i = threadIdx.x; i < 32 * 32; i += blockDim.x) {
    sW2a[i] = W2a[i];
    sW2b[i] = W2b[i];
  }
  if (threadIdx.x < 32) {
    sb2a[threadIdx.x] = b2a[threadIdx.x];
    sb2b[threadIdx.x] = b2b[threadIdx.x];
  }
  __syncthreads();
  int n = blockIdx.x * blockDim.x + threadIdx.x;
  if (n >= N_NODES) return;
  float inv = 1.0f / fmaxf(deg[n], 1.0f);
  float m[32];
  const float* a = agg2 + (size_t)n * 32;
#pragma unroll
  for (int i = 0; i < 32; ++i) m[i] = a[i] * inv;
  float t[32];
#pragma unroll
  for (int j = 0; j < 32; ++j) {
    float acc = sb2a[j];
#pragma unroll
    for (int i = 0; i < 32; ++i) acc += m[i] * sW2a[i * 32 + j];
    t[j] = fmaxf(acc, 0.0f);
  }
  int g = graph_ids[n];
  unsigned int* p = pooled_u + (size_t)g * 32;
#pragma unroll
  for (int j = 0; j < 32; ++j) {
    float acc = sb2b[j];
#pragma unroll
    for (int i = 0; i < 32; ++i) acc += t[i] * sW2b[i * 32 + j];
    float h = fmaxf(acc, 0.0f);
    atomicMax(p + j, __float_as_uint(h));  // valid: h >= 0
  }
}

// ---------------------------------------------------------------------------
// Classifier: 64 graphs, one thread each. relu(pooled@Wm1+bm1)@Wm2+bm2,
// softmax over 2 classes.
// ---------------------------------------------------------------------------
__global__ __launch_bounds__(64) void classifier(
    const unsigned int* __restrict__ pooled_u,
    const float* __restrict__ Wm1, const float* __restrict__ bm1,
    const float* __restrict__ Wm2, const float* __restrict__ bm2,
    float* __restrict__ out) {
  int g = threadIdx.x;
  if (g >= N_GRAPHS) return;
  float p[32];
#pragma unroll
  for (int i = 0; i < 32; ++i) p[i] = __uint_as_float(pooled_u[(size_t)g * 32 + i]);
  float t[16];
#pragma unroll
  for (int j = 0; j < 16; ++j) {
    float acc = bm1[j];
#pragma unroll
    for (int i = 0; i < 32; ++i) acc += p[i] * Wm1[i * 16 + j];
    t[j] = fmaxf(acc, 0.0f);
  }
  float l0 = bm2[0], l1 = bm2[1];
#pragma unroll
  for (int i = 0; i < 16; ++i) {
    l0 += t[i] * Wm2[i * 2 + 0];
    l1 += t[i] * Wm2[i * 2 + 1];
  }
  float mx = fmaxf(l0, l1);
  float e0 = expf(l0 - mx), e1 = expf(l1 - mx);
  float s = e0 + e1;
  out[g * 2 + 0] = e0 / s;
  out[g * 2 + 1] = e1 / s;
}

// ---------------------------------------------------------------------------
extern "C" void kernel_launch(void* const* d_in, const int* in_sizes, int n_in,
                              void* d_out, int out_size, void* d_ws, size_t ws_size,
                              hipStream_t stream) {
  const float* node_feat = (const float*)d_in[0];
  const float* edge_feat = (const float*)d_in[1];
  const int*   src       = (const int*)d_in[2];
  const int*   dst       = (const int*)d_in[3];
  const int*   graph_ids = (const int*)d_in[4];
  const float* W1a = (const float*)d_in[5],  *b1a = (const float*)d_in[6];
  const float* W1b = (const float*)d_in[7],  *b1b = (const float*)d_in[8];
  const float* W2a = (const float*)d_in[9],  *b2a = (const float*)d_in[10];
  const float* W2b = (const float*)d_in[11], *b2b = (const float*)d_in[12];
  const float* Wm1 = (const float*)d_in[13], *bm1 = (const float*)d_in[14];
  const float* Wm2 = (const float*)d_in[15], *bm2 = (const float*)d_in[16];
  float* out = (float*)d_out;

  // Workspace layout. Region [0, zero_bytes) must be zeroed every call
  // (harness poisons ws with 0xAA).
  char* ws = (char*)d_ws;
  size_t off = 0;
  auto take = [&](size_t bytes) {
    char* p = ws + off;
    off = (off + bytes + 255) & ~(size_t)255;
    return p;
  };
  float*        deg      = (float*)take((size_t)N_NODES * 4);            // N
  float*        agg1     = (float*)take((size_t)N_NODES * 11 * 4);       // N x 11
  float*        agg2     = (float*)take((size_t)N_NODES * 32 * 4);       // N x 32
  unsigned int* pooled_u = (unsigned int*)take((size_t)N_GRAPHS * 32 * 4);
  size_t zero_bytes = off;
  float*        h1       = (float*)take((size_t)N_NODES * 32 * 4);       // N x 32
  (void)ws_size; (void)in_sizes; (void)n_in; (void)out_size; (void)h1;

  hipMemsetAsync(d_ws, 0, zero_bytes, stream);

  // Layer 1 scatter
  {
    int grid = (N_EDGES + 255) / 256;
    hipLaunchKernelGGL(edge_pass1, dim3(grid), dim3(256), 0, stream,
                       edge_feat, node_feat, src, dst, agg1, deg);
  }
  // MLP 1
  {
    int grid = (N_NODES + 255) / 256;
    hipLaunchKernelGGL(mlp1, dim3(grid), dim3(256), 0, stream,
                       agg1, deg, W1a, b1a, W1b, b1b, h1);
  }
  // Layer 2 scatter (32 lanes per edge)
  {
    int grid = 65536;
    hipLaunchKernelGGL(edge_pass2, dim3(grid), dim3(256), 0, stream,
                       h1, src, dst, agg2);
  }
  // MLP 2 + max pool
  {
    int grid = (N_NODES + 255) / 256;
    hipLaunchKernelGGL(mlp2_pool, dim3(grid), dim3(256), 0, stream,
                       agg2, deg, graph_ids, W2a, b2a, W2b, b2b, pooled_u);
  }
  // Classifier + softmax
  hipLaunchKernelGGL(classifier, dim3(1), dim3(64), 0, stream,
                     pooled_u, Wm1, bm1, Wm2, bm2, out);
}

// Round 2
// 2494.577 us; speedup vs baseline: 2.8359x; 2.8359x over previous
//
#include <hip/hip_runtime.h>
#include <math.h>

#define N_NODES  200000
#define N_EDGES  6400000
#define N_GRAPHS 64
#define SCAN_CHUNK 2048
#define SCAN_BLOCKS ((N_NODES + SCAN_CHUNK - 1) / SCAN_CHUNK)  // 98

// ---------------------------------------------------------------------------
// CSR build step 1: in-degree histogram (int atomics, scattered but cheap).
// ---------------------------------------------------------------------------
__global__ __launch_bounds__(256) void hist_kernel(
    const int* __restrict__ dst, unsigned int* __restrict__ cnt) {
  int e = blockIdx.x * 256 + threadIdx.x;
  if (e < N_EDGES) atomicAdd(&cnt[dst[e]], 1u);
}

// ---------------------------------------------------------------------------
// CSR build step 2a: per-chunk exclusive scan (each block scans SCAN_CHUNK).
// ---------------------------------------------------------------------------
__global__ __launch_bounds__(256) void scan1(
    const unsigned int* __restrict__ cnt,
    unsigned int* __restrict__ ptr,
    unsigned int* __restrict__ blocksums) {
  __shared__ unsigned int s[256];
  int b = blockIdx.x, t = threadIdx.x;
  int base = b * SCAN_CHUNK + t * 8;
  unsigned int v[8];
  unsigned int sum = 0;
#pragma unroll
  for (int k = 0; k < 8; ++k) {
    int i = base + k;
    v[k] = (i < N_NODES) ? cnt[i] : 0u;
    sum += v[k];
  }
  s[t] = sum;
  __syncthreads();
  for (int off = 1; off < 256; off <<= 1) {
    unsigned int x = (t >= off) ? s[t - off] : 0u;
    __syncthreads();
    s[t] += x;
    __syncthreads();
  }
  unsigned int run = s[t] - sum;  // exclusive offset of this thread
  if (t == 255) blocksums[b] = s[255];
#pragma unroll
  for (int k = 0; k < 8; ++k) {
    int i = base + k;
    if (i < N_NODES) ptr[i] = run;
    run += v[k];
  }
}

// CSR build step 2b: serial exclusive scan of the 98 block sums (tiny).
__global__ void scan2(unsigned int* blocksums) {
  if (threadIdx.x == 0) {
    unsigned int acc = 0;
    for (int i = 0; i < SCAN_BLOCKS; ++i) {
      unsigned int v = blocksums[i];
      blocksums[i] = acc;
      acc += v;
    }
  }
}

// CSR build step 2c: add block offsets; also init the scatter cursor `fill`.
__global__ __launch_bounds__(256) void scan3(
    unsigned int* __restrict__ ptr,
    const unsigned int* __restrict__ blocksums,
    unsigned int* __restrict__ fill) {
  int b = blockIdx.x;
  unsigned int off = blocksums[b];
  int base = b * SCAN_CHUNK + threadIdx.x * 8;
#pragma unroll
  for (int k = 0; k < 8; ++k) {
    int i = base + k;
    if (i < N_NODES) {
      unsigned int p = ptr[i] + off;
      ptr[i] = p;
      fill[i] = p;
    }
  }
}

// ---------------------------------------------------------------------------
// CSR build step 3: scatter edge ids into dst-grouped order.
// ---------------------------------------------------------------------------
__global__ __launch_bounds__(256) void scatter_csr(
    const int* __restrict__ dst,
    unsigned int* __restrict__ fill,
    unsigned int* __restrict__ csr_eid) {
  int e = blockIdx.x * 256 + threadIdx.x;
  if (e < N_EDGES) {
    unsigned int pos = atomicAdd(&fill[dst[e]], 1u);
    csr_eid[pos] = (unsigned int)e;
  }
}

// ---------------------------------------------------------------------------
// Layer 1 (gather form) fused with MLP1. One thread per node: mean over
// in-edges of concat(edge_feat[e], node_feat[src[e]]), then 2-layer MLP.
// No float atomics.
// ---------------------------------------------------------------------------
__global__ __launch_bounds__(256) void gather1_mlp1(
    const unsigned int* __restrict__ ptr,
    const unsigned int* __restrict__ cnt,
    const unsigned int* __restrict__ csr_eid,
    const int* __restrict__ src,
    const float* __restrict__ edge_feat,
    const float* __restrict__ node_feat,
    const float* __restrict__ W1a, const float* __restrict__ b1a,
    const float* __restrict__ W1b, const float* __restrict__ b1b,
    float* __restrict__ h1) {
  __shared__ float sW1a[11 * 32];
  __shared__ float sW1b[32 * 32];
  __shared__ float sb1a[32];
  __shared__ float sb1b[32];
  for (int i = threadIdx.x; i < 11 * 32; i += blockDim.x) sW1a[i] = W1a[i];
  for (int i = threadIdx.x; i < 32 * 32; i += blockDim.x) sW1b[i] = W1b[i];
  if (threadIdx.x < 32) {
    sb1a[threadIdx.x] = b1a[threadIdx.x];
    sb1b[threadIdx.x] = b1b[threadIdx.x];
  }
  __syncthreads();
  int n = blockIdx.x * blockDim.x + threadIdx.x;
  if (n >= N_NODES) return;
  unsigned int start = ptr[n];
  unsigned int c = cnt[n];
  float acc[11];
#pragma unroll
  for (int i = 0; i < 11; ++i) acc[i] = 0.0f;
  for (unsigned int j = 0; j < c; ++j) {
    unsigned int e = csr_eid[start + j];
    int s = src[e];
    const float4 ef = *reinterpret_cast<const float4*>(edge_feat + (size_t)e * 4);
    acc[0] += ef.x; acc[1] += ef.y; acc[2] += ef.z; acc[3] += ef.w;
    const float* nf = node_feat + (size_t)s * 7;
#pragma unroll
    for (int k = 0; k < 7; ++k) acc[4 + k] += nf[k];
  }
  float inv = (c > 0) ? (1.0f / (float)c) : 1.0f;
  float m[11];
#pragma unroll
  for (int i = 0; i < 11; ++i) m[i] = acc[i] * inv;
  float t[32];
#pragma unroll
  for (int j = 0; j < 32; ++j) {
    float a = sb1a[j];
#pragma unroll
    for (int i = 0; i < 11; ++i) a += m[i] * sW1a[i * 32 + j];
    t[j] = fmaxf(a, 0.0f);
  }
  float* out = h1 + (size_t)n * 32;
#pragma unroll
  for (int j = 0; j < 32; ++j) {
    float a = sb1b[j];
#pragma unroll
    for (int i = 0; i < 32; ++i) a += t[i] * sW1b[i * 32 + j];
    out[j] = fmaxf(a, 0.0f);
  }
}

// ---------------------------------------------------------------------------
// Layer 2 (gather form) fused with MLP2 + per-graph max pool.
// 32 lanes per node: lane k owns feature k. h1[src] gathers are coalesced
// 128B loads; MLP done cross-lane via __shfl(width=32). Only 32 atomicMax
// per node (coalesced, 2048 distinct addresses).
// ---------------------------------------------------------------------------
__global__ __launch_bounds__(256) void gather2_mlp2_pool(
    const unsigned int* __restrict__ ptr,
    const unsigned int* __restrict__ cnt,
    const unsigned int* __restrict__ csr_eid,
    const int* __restrict__ src,
    const float* __restrict__ h1,
    const int* __restrict__ graph_ids,
    const float* __restrict__ W2a, const float* __restrict__ b2a,
    const float* __restrict__ W2b, const float* __restrict__ b2b,
    unsigned int* __restrict__ pooled_u) {
  __shared__ float sW2a[32 * 32];
  __shared__ float sW2b[32 * 32];
  __shared__ float sb2a[32];
  __shared__ float sb2b[32];
  for (int i = threadIdx.x; i < 32 * 32; i += blockDim.x) {
    sW2a[i] = W2a[i];
    sW2b[i] = W2b[i];
  }
  if (threadIdx.x < 32) {
    sb2a[threadIdx.x] = b2a[threadIdx.x];
    sb2b[threadIdx.x] = b2b[threadIdx.x];
  }
  __syncthreads();
  const int lane = threadIdx.x & 31;
  int n = blockIdx.x * (blockDim.x / 32) + (threadIdx.x >> 5);
  if (n >= N_NODES) return;
  unsigned int start = ptr[n];
  unsigned int c = cnt[n];
  float acc = 0.0f;
  for (unsigned int j = 0; j < c; ++j) {
    unsigned int e = csr_eid[start + j];  // lane-uniform -> broadcast
    int s = src[e];                        // lane-uniform -> broadcast
    acc += h1[(size_t)s * 32 + lane];      // coalesced 128B
  }
  float inv = (c > 0) ? (1.0f / (float)c) : 1.0f;
  float m = acc * inv;
  // t[lane] = relu(b2a + sum_i m_i * W2a[i][lane])
  float t = sb2a[lane];
#pragma unroll
  for (int i = 0; i < 32; ++i) {
    float mi = __shfl(m, i, 32);
    t += mi * sW2a[i * 32 + lane];
  }
  t = fmaxf(t, 0.0f);
  float h = sb2b[lane];
#pragma unroll
  for (int i = 0; i < 32; ++i) {
    float ti = __shfl(t, i, 32);
    h += ti * sW2b[i * 32 + lane];
  }
  h = fmaxf(h, 0.0f);
  int g = graph_ids[n];
  atomicMax(pooled_u + (size_t)g * 32 + lane, __float_as_uint(h));  // h >= 0
}

// ---------------------------------------------------------------------------
// Classifier: 64 graphs, one thread each.
// ---------------------------------------------------------------------------
__global__ __launch_bounds__(64) void classifier(
    const unsigned int* __restrict__ pooled_u,
    const float* __restrict__ Wm1, const float* __restrict__ bm1,
    const float* __restrict__ Wm2, const float* __restrict__ bm2,
    float* __restrict__ out) {
  int g = threadIdx.x;
  if (g >= N_GRAPHS) return;
  float p[32];
#pragma unroll
  for (int i = 0; i < 32; ++i) p[i] = __uint_as_float(pooled_u[(size_t)g * 32 + i]);
  float t[16];
#pragma unroll
  for (int j = 0; j < 16; ++j) {
    float acc = bm1[j];
#pragma unroll
    for (int i = 0; i < 32; ++i) acc += p[i] * Wm1[i * 16 + j];
    t[j] = fmaxf(acc, 0.0f);
  }
  float l0 = bm2[0], l1 = bm2[1];
#pragma unroll
  for (int i = 0; i < 16; ++i) {
    l0 += t[i] * Wm2[i * 2 + 0];
    l1 += t[i] * Wm2[i * 2 + 1];
  }
  float mx = fmaxf(l0, l1);
  float e0 = expf(l0 - mx), e1 = expf(l1 - mx);
  float s = e0 + e1;
  out[g * 2 + 0] = e0 / s;
  out[g * 2 + 1] = e1 / s;
}

// ---------------------------------------------------------------------------
extern "C" void kernel_launch(void* const* d_in, const int* in_sizes, int n_in,
                              void* d_out, int out_size, void* d_ws, size_t ws_size,
                              hipStream_t stream) {
  const float* node_feat = (const float*)d_in[0];
  const float* edge_feat = (const float*)d_in[1];
  const int*   src       = (const int*)d_in[2];
  const int*   dst       = (const int*)d_in[3];
  const int*   graph_ids = (const int*)d_in[4];
  const float* W1a = (const float*)d_in[5],  *b1a = (const float*)d_in[6];
  const float* W1b = (const float*)d_in[7],  *b1b = (const float*)d_in[8];
  const float* W2a = (const float*)d_in[9],  *b2a = (const float*)d_in[10];
  const float* W2b = (const float*)d_in[11], *b2b = (const float*)d_in[12];
  const float* Wm1 = (const float*)d_in[13], *bm1 = (const float*)d_in[14];
  const float* Wm2 = (const float*)d_in[15], *bm2 = (const float*)d_in[16];
  float* out = (float*)d_out;

  // Workspace layout; [0, zero_bytes) is memset to 0 every call.
  char* ws = (char*)d_ws;
  size_t off = 0;
  auto take = [&](size_t bytes) {
    char* p = ws + off;
    off = (off + bytes + 255) & ~(size_t)255;
    return p;
  };
  unsigned int* cnt      = (unsigned int*)take((size_t)N_NODES * 4);      // zeroed
  unsigned int* pooled_u = (unsigned int*)take((size_t)N_GRAPHS * 32 * 4); // zeroed
  size_t zero_bytes = off;
  unsigned int* ptr      = (unsigned int*)take((size_t)N_NODES * 4);
  unsigned int* fill     = (unsigned int*)take((size_t)N_NODES * 4);
  unsigned int* blocksums= (unsigned int*)take((size_t)SCAN_BLOCKS * 4);
  unsigned int* csr_eid  = (unsigned int*)take((size_t)N_EDGES * 4);
  float*        h1       = (float*)take((size_t)N_NODES * 32 * 4);
  (void)ws_size; (void)in_sizes; (void)n_in; (void)out_size;

  hipMemsetAsync(d_ws, 0, zero_bytes, stream);

  const int egrid = (N_EDGES + 255) / 256;
  hipLaunchKernelGGL(hist_kernel, dim3(egrid), dim3(256), 0, stream, dst, cnt);
  hipLaunchKernelGGL(scan1, dim3(SCAN_BLOCKS), dim3(256), 0, stream, cnt, ptr, blocksums);
  hipLaunchKernelGGL(scan2, dim3(1), dim3(64), 0, stream, blocksums);
  hipLaunchKernelGGL(scan3, dim3(SCAN_BLOCKS), dim3(256), 0, stream, ptr, blocksums, fill);
  hipLaunchKernelGGL(scatter_csr, dim3(egrid), dim3(256), 0, stream, dst, fill, csr_eid);

  hipLaunchKernelGGL(gather1_mlp1, dim3((N_NODES + 255) / 256), dim3(256), 0, stream,
                     ptr, cnt, csr_eid, src, edge_feat, node_feat,
                     W1a, b1a, W1b, b1b, h1);

  hipLaunchKernelGGL(gather2_mlp2_pool, dim3((N_NODES + 7) / 8), dim3(256), 0, stream,
                     ptr, cnt, csr_eid, src, h1, graph_ids,
                     W2a, b2a, W2b, b2b, pooled_u);

  hipLaunchKernelGGL(classifier, dim3(1), dim3(64), 0, stream,
                     pooled_u, Wm1, bm1, Wm2, bm2, out);
}

// Round 3
// 1444.902 us; speedup vs baseline: 4.8960x; 1.7265x over previous
//
#include <hip/hip_runtime.h>
#include <hip/hip_fp16.h>
#include <math.h>

#define N_NODES  200000
#define N_EDGES  6400000
#define N_GRAPHS 64
#define SCAN_CHUNK 2048
#define SCAN_BLOCKS ((N_NODES + SCAN_CHUNK - 1) / SCAN_CHUNK)  // 98

typedef unsigned long long ull;

// ---------------------------------------------------------------------------
// Precompute g = node_feat @ W1a[4:11,:]  (N x 32, fp16). Warp per node.
// ---------------------------------------------------------------------------
__global__ __launch_bounds__(256) void proj_g(
    const float* __restrict__ node_feat,
    const float* __restrict__ W1a,
    __half* __restrict__ g16) {
  __shared__ float sW[7 * 32];
  for (int i = threadIdx.x; i < 7 * 32; i += 256) sW[i] = W1a[4 * 32 + i];
  __syncthreads();
  int n = blockIdx.x * 8 + (threadIdx.x >> 5);   // grid exact: 25000*8 = 200000
  int lane = threadIdx.x & 31;
  const float* nf = node_feat + (size_t)n * 7;
  float a = 0.0f;
#pragma unroll
  for (int k = 0; k < 7; ++k) a += nf[k] * sW[k * 32 + lane];
  g16[(size_t)n * 32 + lane] = __float2half(a);
}

// ---------------------------------------------------------------------------
// CSR build: histogram, 3-step scan, scatter of packed (eid<<32 | src).
// ---------------------------------------------------------------------------
__global__ __launch_bounds__(256) void hist_kernel(
    const int* __restrict__ dst, unsigned int* __restrict__ cnt) {
  int e = blockIdx.x * 256 + threadIdx.x;   // grid exact: 25000*256 = 6.4M
  atomicAdd(&cnt[dst[e]], 1u);
}

__global__ __launch_bounds__(256) void scan1(
    const unsigned int* __restrict__ cnt,
    unsigned int* __restrict__ ptr,
    unsigned int* __restrict__ blocksums) {
  __shared__ unsigned int s[256];
  int b = blockIdx.x, t = threadIdx.x;
  int base = b * SCAN_CHUNK + t * 8;
  unsigned int v[8];
  unsigned int sum = 0;
#pragma unroll
  for (int k = 0; k < 8; ++k) {
    int i = base + k;
    v[k] = (i < N_NODES) ? cnt[i] : 0u;
    sum += v[k];
  }
  s[t] = sum;
  __syncthreads();
  for (int off = 1; off < 256; off <<= 1) {
    unsigned int x = (t >= off) ? s[t - off] : 0u;
    __syncthreads();
    s[t] += x;
    __syncthreads();
  }
  unsigned int run = s[t] - sum;
  if (t == 255) blocksums[b] = s[255];
#pragma unroll
  for (int k = 0; k < 8; ++k) {
    int i = base + k;
    if (i < N_NODES) ptr[i] = run;
    run += v[k];
  }
}

__global__ void scan2(unsigned int* blocksums) {
  if (threadIdx.x == 0) {
    unsigned int acc = 0;
    for (int i = 0; i < SCAN_BLOCKS; ++i) {
      unsigned int v = blocksums[i];
      blocksums[i] = acc;
      acc += v;
    }
  }
}

__global__ __launch_bounds__(256) void scan3(
    unsigned int* __restrict__ ptr,
    const unsigned int* __restrict__ blocksums,
    unsigned int* __restrict__ fill) {
  int b = blockIdx.x;
  unsigned int off = blocksums[b];
  int base = b * SCAN_CHUNK + threadIdx.x * 8;
#pragma unroll
  for (int k = 0; k < 8; ++k) {
    int i = base + k;
    if (i < N_NODES) {
      unsigned int p = ptr[i] + off;
      ptr[i] = p;
      fill[i] = p;
    }
  }
}

__global__ __launch_bounds__(256) void scatter_csr(
    const int* __restrict__ src,
    const int* __restrict__ dst,
    unsigned int* __restrict__ fill,
    ull* __restrict__ packed) {
  int e = blockIdx.x * 256 + threadIdx.x;   // exact grid
  unsigned int pos = atomicAdd(&fill[dst[e]], 1u);
  packed[pos] = ((ull)(unsigned int)e << 32) | (unsigned int)src[e];
}

// ---------------------------------------------------------------------------
// Layer 1 + MLP1. Warp per node. Batched shfl-broadcast of 32 packed records
// per coalesced load; 4 independent g-row gathers in flight; ef gathered by
// 4-lane groups (8 edges in flight). MLPs cross-lane via shfl.
// ---------------------------------------------------------------------------
__global__ __launch_bounds__(256) void gather1_mlp1(
    const unsigned int* __restrict__ ptr,
    const unsigned int* __restrict__ cnt,
    const ull* __restrict__ packed,
    const float* __restrict__ edge_feat,
    const __half* __restrict__ g16,
    const float* __restrict__ W1a, const float* __restrict__ b1a,
    const float* __restrict__ W1b, const float* __restrict__ b1b,
    __half* __restrict__ h1) {
  __shared__ float sWef[4 * 32];
  __shared__ float sW1b[32 * 32];
  __shared__ float sb1a[32], sb1b[32];
  for (int i = threadIdx.x; i < 4 * 32; i += 256) sWef[i] = W1a[i];
  for (int i = threadIdx.x; i < 32 * 32; i += 256) sW1b[i] = W1b[i];
  if (threadIdx.x < 32) {
    sb1a[threadIdx.x] = b1a[threadIdx.x];
    sb1b[threadIdx.x] = b1b[threadIdx.x];
  }
  __syncthreads();
  const int lane = threadIdx.x & 31;
  const int grp = lane >> 2, comp = lane & 3;
  int n = blockIdx.x * 8 + (threadIdx.x >> 5);   // exact grid
  unsigned int start = ptr[n];
  unsigned int c = cnt[n];
  float accg = 0.0f, accef = 0.0f;
  for (unsigned int base = 0; base < c; base += 32) {
    unsigned int m = min(32u, c - base);
    int my_s = 0, my_e = 0;
    if (lane < m) {
      ull pk = packed[start + base + lane];
      my_s = (int)(unsigned int)pk;
      my_e = (int)(unsigned int)(pk >> 32);
    }
    // g-row gathers: 4 independent loads per step
    unsigned int j = 0;
    for (; j + 4 <= m; j += 4) {
      int s0 = __shfl(my_s, (int)j, 32);
      int s1 = __shfl(my_s, (int)j + 1, 32);
      int s2 = __shfl(my_s, (int)j + 2, 32);
      int s3 = __shfl(my_s, (int)j + 3, 32);
      float v0 = __half2float(g16[(size_t)s0 * 32 + lane]);
      float v1 = __half2float(g16[(size_t)s1 * 32 + lane]);
      float v2 = __half2float(g16[(size_t)s2 * 32 + lane]);
      float v3 = __half2float(g16[(size_t)s3 * 32 + lane]);
      accg += (v0 + v1) + (v2 + v3);
    }
    for (; j < m; ++j) {
      int s = __shfl(my_s, (int)j, 32);
      accg += __half2float(g16[(size_t)s * 32 + lane]);
    }
    // ef gathers: 8 edges per pass, 4-lane groups
    unsigned int sub = 0;
    for (; sub + 8 <= m; sub += 8) {
      int e = __shfl(my_e, (int)sub + grp, 32);
      accef += edge_feat[(size_t)e * 4 + comp];
    }
    if (sub < m) {
      int e = __shfl(my_e, (int)sub + grp, 32);
      if ((unsigned int)grp < m - sub) accef += edge_feat[(size_t)e * 4 + comp];
    }
  }
  // reduce ef partials: lanes sharing comp across the 8 groups
  accef += __shfl_xor(accef, 4, 32);
  accef += __shfl_xor(accef, 8, 32);
  accef += __shfl_xor(accef, 16, 32);
  float sA = accef;                       // S[comp]
  float sB = __shfl_xor(sA, 1, 32);       // S[comp^1]
  float sC = __shfl_xor(sA, 2, 32);       // S[comp^2]
  float sD = __shfl_xor(sA, 3, 32);       // S[comp^3]
  float S0 = (comp == 0) ? sA : (comp == 1) ? sB : (comp == 2) ? sC : sD;
  float S1 = (comp == 1) ? sA : (comp == 0) ? sB : (comp == 3) ? sC : sD;
  float S2 = (comp == 2) ? sA : (comp == 3) ? sB : (comp == 0) ? sC : sD;
  float S3 = (comp == 3) ? sA : (comp == 2) ? sB : (comp == 1) ? sC : sD;
  float inv = (c > 0) ? (1.0f / (float)c) : 1.0f;
  float u = sb1a[lane] + accg * inv +
            inv * (S0 * sWef[0 * 32 + lane] + S1 * sWef[1 * 32 + lane] +
                   S2 * sWef[2 * 32 + lane] + S3 * sWef[3 * 32 + lane]);
  u = fmaxf(u, 0.0f);
  float h = sb1b[lane];
#pragma unroll
  for (int i = 0; i < 32; ++i) h += __shfl(u, i, 32) * sW1b[i * 32 + lane];
  h = fmaxf(h, 0.0f);
  h1[(size_t)n * 32 + lane] = __float2half(h);
}

// ---------------------------------------------------------------------------
// Layer 2 + MLP2 + pooling. Warp per node; fp16 h1 rows (one 64B line each);
// block-level LDS max-reduce before global atomicMax (graph_ids sorted).
// ---------------------------------------------------------------------------
__global__ __launch_bounds__(256) void gather2_mlp2_pool(
    const unsigned int* __restrict__ ptr,
    const unsigned int* __restrict__ cnt,
    const ull* __restrict__ packed,
    const __half* __restrict__ h1,
    const int* __restrict__ graph_ids,
    const float* __restrict__ W2a, const float* __restrict__ b2a,
    const float* __restrict__ W2b, const float* __restrict__ b2b,
    unsigned int* __restrict__ pooled_u) {
  __shared__ float sW2a[32 * 32], sW2b[32 * 32];
  __shared__ float sb2a[32], sb2b[32];
  __shared__ float red[8][32];
  __shared__ int sgid[8];
  for (int i = threadIdx.x; i < 32 * 32; i += 256) {
    sW2a[i] = W2a[i];
    sW2b[i] = W2b[i];
  }
  if (threadIdx.x < 32) {
    sb2a[threadIdx.x] = b2a[threadIdx.x];
    sb2b[threadIdx.x] = b2b[threadIdx.x];
  }
  __syncthreads();
  const int lane = threadIdx.x & 31;
  const int w = threadIdx.x >> 5;
  int n = blockIdx.x * 8 + w;   // exact grid
  unsigned int start = ptr[n];
  unsigned int c = cnt[n];
  float acc = 0.0f;
  for (unsigned int base = 0; base < c; base += 32) {
    unsigned int m = min(32u, c - base);
    int my_s = 0;
    if (lane < m) my_s = (int)(unsigned int)packed[start + base + lane];
    unsigned int j = 0;
    for (; j + 4 <= m; j += 4) {
      int s0 = __shfl(my_s, (int)j, 32);
      int s1 = __shfl(my_s, (int)j + 1, 32);
      int s2 = __shfl(my_s, (int)j + 2, 32);
      int s3 = __shfl(my_s, (int)j + 3, 32);
      float v0 = __half2float(h1[(size_t)s0 * 32 + lane]);
      float v1 = __half2float(h1[(size_t)s1 * 32 + lane]);
      float v2 = __half2float(h1[(size_t)s2 * 32 + lane]);
      float v3 = __half2float(h1[(size_t)s3 * 32 + lane]);
      acc += (v0 + v1) + (v2 + v3);
    }
    for (; j < m; ++j) {
      int s = __shfl(my_s, (int)j, 32);
      acc += __half2float(h1[(size_t)s * 32 + lane]);
    }
  }
  float inv = (c > 0) ? (1.0f / (float)c) : 1.0f;
  float mfeat = acc * inv;
  float t = sb2a[lane];
#pragma unroll
  for (int i = 0; i < 32; ++i) t += __shfl(mfeat, i, 32) * sW2a[i * 32 + lane];
  t = fmaxf(t, 0.0f);
  float h = sb2b[lane];
#pragma unroll
  for (int i = 0; i < 32; ++i) h += __shfl(t, i, 32) * sW2b[i * 32 + lane];
  h = fmaxf(h, 0.0f);
  red[w][lane] = h;
  if (lane == 0) sgid[w] = graph_ids[n];
  __syncthreads();
  if (w == 0) {
    int g0 = sgid[0];
    bool same = true;
#pragma unroll
    for (int k = 1; k < 8; ++k) same = same && (sgid[k] == g0);
    if (same) {
      float mx = red[0][lane];
#pragma unroll
      for (int k = 1; k < 8; ++k) mx = fmaxf(mx, red[k][lane]);
      atomicMax(pooled_u + (size_t)g0 * 32 + lane, __float_as_uint(mx));
    } else {
#pragma unroll
      for (int k = 0; k < 8; ++k)
        atomicMax(pooled_u + (size_t)sgid[k] * 32 + lane, __float_as_uint(red[k][lane]));
    }
  }
}

// ---------------------------------------------------------------------------
__global__ __launch_bounds__(64) void classifier(
    const unsigned int* __restrict__ pooled_u,
    const float* __restrict__ Wm1, const float* __restrict__ bm1,
    const float* __restrict__ Wm2, const float* __restrict__ bm2,
    float* __restrict__ out) {
  int g = threadIdx.x;
  if (g >= N_GRAPHS) return;
  float p[32];
#pragma unroll
  for (int i = 0; i < 32; ++i) p[i] = __uint_as_float(pooled_u[(size_t)g * 32 + i]);
  float t[16];
#pragma unroll
  for (int j = 0; j < 16; ++j) {
    float acc = bm1[j];
#pragma unroll
    for (int i = 0; i < 32; ++i) acc += p[i] * Wm1[i * 16 + j];
    t[j] = fmaxf(acc, 0.0f);
  }
  float l0 = bm2[0], l1 = bm2[1];
#pragma unroll
  for (int i = 0; i < 16; ++i) {
    l0 += t[i] * Wm2[i * 2 + 0];
    l1 += t[i] * Wm2[i * 2 + 1];
  }
  float mx = fmaxf(l0, l1);
  float e0 = expf(l0 - mx), e1 = expf(l1 - mx);
  float s = e0 + e1;
  out[g * 2 + 0] = e0 / s;
  out[g * 2 + 1] = e1 / s;
}

// ---------------------------------------------------------------------------
extern "C" void kernel_launch(void* const* d_in, const int* in_sizes, int n_in,
                              void* d_out, int out_size, void* d_ws, size_t ws_size,
                              hipStream_t stream) {
  const float* node_feat = (const float*)d_in[0];
  const float* edge_feat = (const float*)d_in[1];
  const int*   src       = (const int*)d_in[2];
  const int*   dst       = (const int*)d_in[3];
  const int*   graph_ids = (const int*)d_in[4];
  const float* W1a = (const float*)d_in[5],  *b1a = (const float*)d_in[6];
  const float* W1b = (const float*)d_in[7],  *b1b = (const float*)d_in[8];
  const float* W2a = (const float*)d_in[9],  *b2a = (const float*)d_in[10];
  const float* W2b = (const float*)d_in[11], *b2b = (const float*)d_in[12];
  const float* Wm1 = (const float*)d_in[13], *bm1 = (const float*)d_in[14];
  const float* Wm2 = (const float*)d_in[15], *bm2 = (const float*)d_in[16];
  float* out = (float*)d_out;

  char* ws = (char*)d_ws;
  size_t off = 0;
  auto take = [&](size_t bytes) {
    char* p = ws + off;
    off = (off + bytes + 255) & ~(size_t)255;
    return p;
  };
  unsigned int* cnt      = (unsigned int*)take((size_t)N_NODES * 4);        // zeroed
  unsigned int* pooled_u = (unsigned int*)take((size_t)N_GRAPHS * 32 * 4);  // zeroed
  size_t zero_bytes = off;
  unsigned int* ptr      = (unsigned int*)take((size_t)N_NODES * 4);
  unsigned int* fill     = (unsigned int*)take((size_t)N_NODES * 4);
  unsigned int* bsums    = (unsigned int*)take((size_t)SCAN_BLOCKS * 4);
  ull*          packed   = (ull*)take((size_t)N_EDGES * 8);                 // 51.2 MB
  __half*       g16      = (__half*)take((size_t)N_NODES * 32 * 2);         // 12.8 MB
  __half*       h1       = (__half*)take((size_t)N_NODES * 32 * 2);         // 12.8 MB
  (void)ws_size; (void)in_sizes; (void)n_in; (void)out_size;

  hipMemsetAsync(d_ws, 0, zero_bytes, stream);

  const int egrid = N_EDGES / 256;   // 25000, exact
  const int ngrid = N_NODES / 8;     // 25000 blocks of 8 warps, exact

  hipLaunchKernelGGL(proj_g, dim3(ngrid), dim3(256), 0, stream, node_feat, W1a, g16);
  hipLaunchKernelGGL(hist_kernel, dim3(egrid), dim3(256), 0, stream, dst, cnt);
  hipLaunchKernelGGL(scan1, dim3(SCAN_BLOCKS), dim3(256), 0, stream, cnt, ptr, bsums);
  hipLaunchKernelGGL(scan2, dim3(1), dim3(64), 0, stream, bsums);
  hipLaunchKernelGGL(scan3, dim3(SCAN_BLOCKS), dim3(256), 0, stream, ptr, bsums, fill);
  hipLaunchKernelGGL(scatter_csr, dim3(egrid), dim3(256), 0, stream, src, dst, fill, packed);

  hipLaunchKernelGGL(gather1_mlp1, dim3(ngrid), dim3(256), 0, stream,
                     ptr, cnt, packed, edge_feat, g16, W1a, b1a, W1b, b1b, h1);

  hipLaunchKernelGGL(gather2_mlp2_pool, dim3(ngrid), dim3(256), 0, stream,
                     ptr, cnt, packed, h1, graph_ids, W2a, b2a, W2b, b2b, pooled_u);

  hipLaunchKernelGGL(classifier, dim3(1), dim3(64), 0, stream,
                     pooled_u, Wm1, bm1, Wm2, bm2, out);
}